// Round 7
// baseline (277.809 us; speedup 1.0000x reference)
//
#include <hip/hip_runtime.h>

#define N_SPIKES 16384
#define N_UNITS  256
#define N_NEIGHB 128
#define RANK     5
#define NC       64
#define NC_OBS   12
#define N_CAND   10
#define DD       60                 // RANK * NC_OBS
#define DD4      15                 // DD / 4
#define OUT_COLS 61
#define OUT_SIZE (N_UNITS * OUT_COLS)   // 15616
#define N_REP    64
#define LIST_CAP 96                 // quarter-bucket mean 32, sd 5.7 -> 11 sigma
#define CHUNK    32

// ---------------------------------------------------------------------------
// Kernel P: w[h,u] = Coo_inv[h] @ nu,  b = log_prop[u] - 0.5 nu.w
// thread = (unit, dim-half).  512 blocks x 128 thr (4 blocks/h, 64 units,
// 2 halves as adjacent lanes -> shfl_xor(1) combine).  nu in padded LDS
// rows (stride 61, conflict-free); C rows via aligned float4 from L1
// (wave-uniform-ish: 2 distinct addresses per instr).  4 waves/CU.
// ---------------------------------------------------------------------------
__global__ __launch_bounds__(128) void precompute_kernel(
    const float* __restrict__ mu, const float* __restrict__ Coo_inv,
    const int* __restrict__ obs_ix, const float* __restrict__ log_prop,
    float* __restrict__ w_buf, float* __restrict__ b_buf)
{
    __shared__ float tile[64 * 61];   // per-unit nu, 15.6 KB

    const int tid  = threadIdx.x;
    const int h    = blockIdx.x >> 2;
    const int q    = blockIdx.x & 3;
    const int ul   = tid >> 1;        // unit-local 0..63
    const int half = tid & 1;         // dim half: 0 -> d[0,32), 1 -> d[32,60)
    const int u    = q * 64 + ul;
    const int p    = h * N_UNITS + u;

    int so[NC_OBS];
#pragma unroll
    for (int j = 0; j < NC_OBS; ++j) so[j] = obs_ix[h * NC_OBS + j];

    const float* __restrict__ mub = mu + u * (RANK * NC);
    float* tl = &tile[ul * 61];
    const int d0   = half ? 32 : 0;
    const int nd   = half ? 28 : 32;
    const int kmax = half ? 7 : 8;    // float4 chunks in this half

    for (int d = d0; d < d0 + nd; ++d) {
        const int r = d / NC_OBS;
        const int j = d - r * NC_OBS;
        tl[d] = mub[r * NC + so[j]];
    }
    __syncthreads();

    float wreg[32];
#pragma unroll
    for (int k = 0; k < 32; ++k) wreg[k] = 0.f;

    const float* __restrict__ C = Coo_inv + h * DD * DD;
    for (int e = 0; e < DD; ++e) {
        const float nue = tl[e];
        const float4* __restrict__ Crow = (const float4*)(C + e * DD + d0);
#pragma unroll
        for (int kc = 0; kc < 8; ++kc) {
            if (kc < kmax) {
                const float4 cv = Crow[kc];
                wreg[4*kc+0] = fmaf(cv.x, nue, wreg[4*kc+0]);
                wreg[4*kc+1] = fmaf(cv.y, nue, wreg[4*kc+1]);
                wreg[4*kc+2] = fmaf(cv.z, nue, wreg[4*kc+2]);
                wreg[4*kc+3] = fmaf(cv.w, nue, wreg[4*kc+3]);
            }
        }
    }

    float q2 = 0.f;
#pragma unroll
    for (int kc = 0; kc < 8; ++kc) {
        if (kc < kmax) {
            q2 += wreg[4*kc+0] * tl[d0 + 4*kc + 0]
                + wreg[4*kc+1] * tl[d0 + 4*kc + 1]
                + wreg[4*kc+2] * tl[d0 + 4*kc + 2]
                + wreg[4*kc+3] * tl[d0 + 4*kc + 3];
        }
    }
    q2 += __shfl_xor(q2, 1, 64);      // combine the two halves (adjacent lanes)

    float4* __restrict__ wout = (float4*)(w_buf + (size_t)p * DD + d0);
#pragma unroll
    for (int kc = 0; kc < 8; ++kc) {
        if (kc < kmax) {
            float4 o;
            o.x = wreg[4*kc+0]; o.y = wreg[4*kc+1];
            o.z = wreg[4*kc+2]; o.w = wreg[4*kc+3];
            wout[kc] = o;
        }
    }
    if (half == 0) b_buf[p] = log_prop[u] - 0.5f * q2;
}

// ---------------------------------------------------------------------------
// Kernel S: h-bucketed DENSE spike pass.  512 blocks (4 per h, spike index
// mod 4), 256 thr.  Per 32-spike chunk:
//   GEMM  S[32][256] = X W_h^T + b   (thread tile 4 spikes x 8 units,
//          units u = 32j+ug so S-writes are bank-conflict-free;
//          X/W streamed from L1/L2 -- 12 independent loads per K-step)
//   softmax over the explicit 10-candidate list (duplicates exact)
//   scatter: one 61-lane ds-atomic instr per (spike,cand)
// Flush: nonzero-skip global atomics into 64 replicas.  LDS ~98 KB.
// ---------------------------------------------------------------------------
__global__ __launch_bounds__(256, 1) void spike_dense_kernel(
    const float* __restrict__ features, const float* __restrict__ noise_lp,
    const int* __restrict__ cands, const int* __restrict__ nid,
    const float* __restrict__ w_buf, const float* __restrict__ b_buf,
    float* __restrict__ rep)
{
    __shared__ float S[CHUNK * N_UNITS];   // 32 KB
    __shared__ float acc[OUT_SIZE];        // 62.5 KB
    __shared__ float sq[CHUNK][N_CAND];
    __shared__ int   su[CHUNK][N_CAND];
    __shared__ int   slist[LIST_CAP];
    __shared__ int   scnt;

    const int tid     = threadIdx.x;
    const int h       = blockIdx.x >> 2;
    const int quarter = blockIdx.x & 3;

    if (tid == 0) scnt = 0;
    for (int i = tid; i < OUT_SIZE; i += 256) acc[i] = 0.f;
    __syncthreads();

    // ---- scan: spikes n with n%4==quarter and nid[n]==h ----
    for (int i = tid; i < N_SPIKES / 4; i += 256) {
        const int n = 4 * i + quarter;
        if (nid[n] == h) {
            const int p = atomicAdd(&scnt, 1);
            if (p < LIST_CAP) slist[p] = n;
        }
    }
    __syncthreads();
    const int cnt = (scnt < LIST_CAP) ? scnt : LIST_CAP;
    for (int i = cnt + tid; i < LIST_CAP; i += 256)
        slist[i] = (cnt > 0) ? slist[0] : 0;   // pad with a safe index
    __syncthreads();

    const float nlp = noise_lp[0];
    const int nchunks = (cnt + CHUNK - 1) / CHUNK;
    const int lane = tid & 63;
    const int wave = tid >> 6;
    const int sg = tid >> 5;          // spike group 0..7 (4 spikes each)
    const int ug = tid & 31;          // unit lane: units 32j+ug
    const float4* __restrict__ f4 = (const float4*)features;
    const float4* __restrict__ w4 = (const float4*)w_buf;

    for (int ch = 0; ch < nchunks; ++ch) {
        const int base = ch * CHUNK;
        const int rem  = ((cnt - base) < CHUNK) ? (cnt - base) : CHUNK;

        // ---- GEMM: thread computes 4 spikes x 8 units ----
        {
            const int n0 = slist[base + sg * 4 + 0];
            const int n1 = slist[base + sg * 4 + 1];
            const int n2 = slist[base + sg * 4 + 2];
            const int n3 = slist[base + sg * 4 + 3];

            float a[4][8];
#pragma unroll
            for (int i = 0; i < 4; ++i)
#pragma unroll
                for (int j = 0; j < 8; ++j) a[i][j] = 0.f;

#pragma unroll 3
            for (int k = 0; k < DD4; ++k) {
                const float4 x0 = f4[n0 * DD4 + k];
                const float4 x1 = f4[n1 * DD4 + k];
                const float4 x2 = f4[n2 * DD4 + k];
                const float4 x3 = f4[n3 * DD4 + k];
                float4 wv[8];
#pragma unroll
                for (int j = 0; j < 8; ++j)
                    wv[j] = w4[((size_t)(h * N_UNITS) + 32 * j + ug) * DD4 + k];
#pragma unroll
                for (int j = 0; j < 8; ++j) {
                    a[0][j] += x0.x*wv[j].x + x0.y*wv[j].y + x0.z*wv[j].z + x0.w*wv[j].w;
                    a[1][j] += x1.x*wv[j].x + x1.y*wv[j].y + x1.z*wv[j].z + x1.w*wv[j].w;
                    a[2][j] += x2.x*wv[j].x + x2.y*wv[j].y + x2.z*wv[j].z + x2.w*wv[j].w;
                    a[3][j] += x3.x*wv[j].x + x3.y*wv[j].y + x3.z*wv[j].z + x3.w*wv[j].w;
                }
            }

            float bb[8];
#pragma unroll
            for (int j = 0; j < 8; ++j)
                bb[j] = b_buf[h * N_UNITS + 32 * j + ug];

#pragma unroll
            for (int i = 0; i < 4; ++i)
#pragma unroll
                for (int j = 0; j < 8; ++j)
                    S[(sg * 4 + i) * N_UNITS + 32 * j + ug] = a[i][j] + bb[j];
        }
        __syncthreads();

        // ---- softmax per spike: 16-lane groups, explicit 10-cand list ----
        {
            const int g = lane >> 4;
            const int c = lane & 15;
#pragma unroll
            for (int r = 0; r < 2; ++r) {
                const int sp = wave * 8 + r * 4 + g;
                if (sp < rem) {
                    const int n = slist[base + sp];
                    int uc = 0; float ll = -1e30f;
                    if (c < N_CAND) {
                        uc = cands[n * N_CAND + c];
                        ll = S[sp * N_UNITS + uc];
                    }
                    float m = fmaxf(ll, nlp);
                    m = fmaxf(m, __shfl_xor(m, 8, 64));
                    m = fmaxf(m, __shfl_xor(m, 4, 64));
                    m = fmaxf(m, __shfl_xor(m, 2, 64));
                    m = fmaxf(m, __shfl_xor(m, 1, 64));
                    float e = (c < N_CAND) ? __expf(ll - m) : 0.f;
                    float z = e;
                    z += __shfl_xor(z, 8, 64);
                    z += __shfl_xor(z, 4, 64);
                    z += __shfl_xor(z, 2, 64);
                    z += __shfl_xor(z, 1, 64);
                    z += __expf(nlp - m);
                    if (c < N_CAND) { sq[sp][c] = e / z; su[sp][c] = uc; }
                }
            }
        }
        __syncthreads();

        // ---- scatter: wave handles 8 spikes; 61 lanes per atomic instr ----
        {
            const int dl = (lane < DD) ? lane : 0;
            for (int i = 0; i < 8; ++i) {
                const int sp = wave * 8 + i;
                if (sp >= rem) break;                 // wave-uniform
                const int n = slist[base + sp];
                const float xf = features[n * DD + dl];
                const float val = (lane < DD) ? xf : 1.f;
#pragma unroll
                for (int cc = 0; cc < N_CAND; ++cc) {
                    const float qq = sq[sp][cc];      // LDS broadcast
                    const int  uu = su[sp][cc];
                    if (lane <= DD) {
                        const int addr = (lane < DD) ? (uu * OUT_COLS + 1 + lane)
                                                     : (uu * OUT_COLS);
                        atomicAdd(&acc[addr], qq * val);
                    }
                }
            }
        }
        __syncthreads();
    }

    // ---- flush: nonzero-skip atomics into one of 64 replicas ----
    float* __restrict__ r = rep + (size_t)(blockIdx.x & (N_REP - 1)) * OUT_SIZE;
    for (int i = tid; i < OUT_SIZE; i += 256) {
        const float v = acc[i];
        if (v != 0.f) atomicAdd(&r[i], v);
    }
}

// ---------------------------------------------------------------------------
// Kernel R: sum 64 replicas -> d_out.  61 blocks x 256 thr (61*256 = 15616).
// ---------------------------------------------------------------------------
__global__ __launch_bounds__(256) void reduce_kernel(
    const float* __restrict__ rep, float* __restrict__ out)
{
    const int i = blockIdx.x * 256 + threadIdx.x;
    float s = 0.f;
#pragma unroll 8
    for (int r = 0; r < N_REP; ++r)
        s += rep[(size_t)r * OUT_SIZE + i];
    out[i] = s;
}

extern "C" void kernel_launch(void* const* d_in, const int* in_sizes, int n_in,
                              void* d_out, int out_size, void* d_ws, size_t ws_size,
                              hipStream_t stream) {
    const float* features    = (const float*)d_in[0];
    const float* mu          = (const float*)d_in[1];
    const float* Coo_inv     = (const float*)d_in[2];
    // d_in[3] = Coo_logdet : unused (cancels in softmax)
    const float* log_prop    = (const float*)d_in[4];
    const float* noise_lp    = (const float*)d_in[5];
    const int*   cands       = (const int*)d_in[6];
    const int*   nid         = (const int*)d_in[7];
    const int*   obs_ix      = (const int*)d_in[8];
    float* out = (float*)d_out;

    char* ws = (char*)d_ws;
    float* w_buf = (float*)ws;                         // 128*256*60*4 = 7,864,320 B
    float* b_buf = (float*)(ws + 7864320);             // 128*256*4    =   131,072 B
    float* rep   = (float*)(ws + 7864320 + 131072);    // 64*15616*4   = 3,997,696 B

    hipMemsetAsync(rep, 0, (size_t)N_REP * OUT_SIZE * sizeof(float), stream);
    precompute_kernel<<<512, 128, 0, stream>>>(mu, Coo_inv, obs_ix, log_prop,
                                               w_buf, b_buf);
    spike_dense_kernel<<<512, 256, 0, stream>>>(features, noise_lp, cands, nid,
                                                w_buf, b_buf, rep);
    reduce_kernel<<<61, 256, 0, stream>>>(rep, out);
}

// Round 8
// 177.068 us; speedup vs baseline: 1.5689x; 1.5689x over previous
//
#include <hip/hip_runtime.h>

#define N_SPIKES 16384
#define N_UNITS  256
#define N_NEIGHB 128
#define RANK     5
#define NC       64
#define NC_OBS   12
#define N_CAND   10
#define DD       60                 // RANK * NC_OBS
#define DD4      15                 // DD / 4
#define OUT_COLS 61
#define OUT_SIZE (N_UNITS * OUT_COLS)   // 15616
#define N_REP    64

// Native fp32 atomics (ds_add_f32 / global_atomic_add_f32). Plain
// atomicAdd(float*) compiles to a CAS retry loop without
// -munsafe-fp-atomics -- that loop was the invisible bottleneck R1-R7.
__device__ __forceinline__ void atom_add(float* p, float v) {
    unsafeAtomicAdd(p, v);
}

// ---------------------------------------------------------------------------
// Kernel P: fused nu-gather + matvec (R4 version -- known correct/fast).
//   w[h,u] = Coo_inv[h] @ nu,  b = log_prop[u] - 0.5 * nu.w
// 256 blocks x 128 thr, lane owns unit.
// ---------------------------------------------------------------------------
__global__ __launch_bounds__(128) void precompute_kernel(
    const float* __restrict__ mu, const float* __restrict__ Coo_inv,
    const int* __restrict__ obs_ix, const float* __restrict__ log_prop,
    float* __restrict__ w_buf, float* __restrict__ b_buf)
{
    __shared__ float tile[128 * 61];

    const int h    = blockIdx.x >> 1;
    const int tid  = threadIdx.x;
    const int lane = tid & 63;
    const int wave = tid >> 6;
    const int u    = (blockIdx.x & 1) * 128 + wave * 64 + lane;
    const int p    = h * N_UNITS + u;

    int so[NC_OBS];
#pragma unroll
    for (int j = 0; j < NC_OBS; ++j) so[j] = obs_ix[h * NC_OBS + j];

    const float* __restrict__ mub = mu + u * (RANK * NC);
    float* tl = &tile[tid * 61];
#pragma unroll
    for (int d = 0; d < DD; ++d) {
        const int r = d / NC_OBS;
        const int j = d - r * NC_OBS;
        tl[d] = mub[r * NC + so[j]];
    }

    float wreg[DD];
#pragma unroll
    for (int d = 0; d < DD; ++d) wreg[d] = 0.f;

    const float* __restrict__ C = Coo_inv + h * DD * DD;
    for (int e = 0; e < DD; ++e) {
        const float nu_e = tl[e];
        const float* __restrict__ Crow = C + e * DD;
#pragma unroll
        for (int d = 0; d < DD; ++d)
            wreg[d] = fmaf(Crow[d], nu_e, wreg[d]);
    }

    float q2 = 0.f;
#pragma unroll
    for (int d = 0; d < DD; ++d) q2 += wreg[d] * tl[d];

#pragma unroll
    for (int k = 0; k < DD4; ++k) {
        float4 o;
        o.x = wreg[4*k+0]; o.y = wreg[4*k+1];
        o.z = wreg[4*k+2]; o.w = wreg[4*k+3];
        ((float4*)w_buf)[p * DD4 + k] = o;
    }
    b_buf[p] = log_prop[u] - 0.5f * q2;
}

// ---------------------------------------------------------------------------
// Kernel S: 16-lane float4 groups, 2 spikes per group with all loads
// hoisted (R6 structure).  256 blocks x 512 thr = 64 spikes/block.
// LDS accumulate via NATIVE ds_add_f32; flush via native global atomics
// into 64 replicated tables.
// ---------------------------------------------------------------------------
__global__ __launch_bounds__(512, 2) void spike_kernel(
    const float* __restrict__ features, const float* __restrict__ noise_lp,
    const int* __restrict__ cands, const int* __restrict__ nid,
    const float* __restrict__ w_buf, const float* __restrict__ b_buf,
    float* __restrict__ rep)
{
    __shared__ float acc[OUT_SIZE];
    const int tid = threadIdx.x;
    for (int i = tid; i < OUT_SIZE; i += 512) acc[i] = 0.f;

    const int lane = tid & 63;
    const int wave = tid >> 6;
    const int l = lane & 15;          // dim-chunk within group
    const int s = lane >> 4;          // group slot within wave
    const bool dimlane = (l < DD4);
    const float nlp = noise_lp[0];
    const float4* __restrict__ f4 = (const float4*)features;
    const float4* __restrict__ w4 = (const float4*)w_buf;
    const float4 z4 = {0.f, 0.f, 0.f, 0.f};

    const int base = blockIdx.x * 64 + wave * 8;
    const int n0 = base + s;          // spike A for this group
    const int n1 = base + 4 + s;      // spike B for this group

    // ---- wavefront of independent loads, round 1 ----
    const int h0 = nid[n0];
    const int h1 = nid[n1];
    const float4 xf0 = dimlane ? f4[n0 * DD4 + l] : z4;
    const float4 xf1 = dimlane ? f4[n1 * DD4 + l] : z4;
    int uc0[N_CAND], uc1[N_CAND];
#pragma unroll
    for (int c = 0; c < N_CAND; ++c) {
        uc0[c] = cands[n0 * N_CAND + c];
        uc1[c] = cands[n1 * N_CAND + c];
    }

    // ---- round 2: all 20 gathers + 20 bias loads issued together ----
    float4 wv0[N_CAND], wv1[N_CAND];
    float  bb0[N_CAND], bb1[N_CAND];
#pragma unroll
    for (int c = 0; c < N_CAND; ++c) {
        const int p0 = h0 * N_UNITS + uc0[c];
        const int p1 = h1 * N_UNITS + uc1[c];
        wv0[c] = dimlane ? w4[p0 * DD4 + l] : z4;
        wv1[c] = dimlane ? w4[p1 * DD4 + l] : z4;
        bb0[c] = b_buf[p0];
        bb1[c] = b_buf[p1];
    }

    // ---- compute: dot + 4-step 16-lane reduce, both spikes ----
    float ll0[N_CAND], ll1[N_CAND];
#pragma unroll
    for (int c = 0; c < N_CAND; ++c) {
        float t0 = wv0[c].x*xf0.x + wv0[c].y*xf0.y + wv0[c].z*xf0.z + wv0[c].w*xf0.w;
        float t1 = wv1[c].x*xf1.x + wv1[c].y*xf1.y + wv1[c].z*xf1.z + wv1[c].w*xf1.w;
        t0 += __shfl_xor(t0, 8, 64); t1 += __shfl_xor(t1, 8, 64);
        t0 += __shfl_xor(t0, 4, 64); t1 += __shfl_xor(t1, 4, 64);
        t0 += __shfl_xor(t0, 2, 64); t1 += __shfl_xor(t1, 2, 64);
        t0 += __shfl_xor(t0, 1, 64); t1 += __shfl_xor(t1, 1, 64);
        ll0[c] = bb0[c] + t0;
        ll1[c] = bb1[c] + t1;
    }

    float m0 = nlp, m1 = nlp;
#pragma unroll
    for (int c = 0; c < N_CAND; ++c) { m0 = fmaxf(m0, ll0[c]); m1 = fmaxf(m1, ll1[c]); }
    float s0 = __expf(nlp - m0), s1 = __expf(nlp - m1);
    float qv0[N_CAND], qv1[N_CAND];
#pragma unroll
    for (int c = 0; c < N_CAND; ++c) {
        qv0[c] = __expf(ll0[c] - m0); s0 += qv0[c];
        qv1[c] = __expf(ll1[c] - m1); s1 += qv1[c];
    }
    const float inv0 = 1.f / s0, inv1 = 1.f / s1;

    __syncthreads();   // acc zero-init complete

#pragma unroll
    for (int c = 0; c < N_CAND; ++c) {
        const float q0 = qv0[c] * inv0;
        const float q1 = qv1[c] * inv1;
        const int ub0 = uc0[c] * OUT_COLS;
        const int ub1 = uc1[c] * OUT_COLS;
        if (dimlane) {
            const int a0 = ub0 + 1 + l * 4;
            atom_add(&acc[a0 + 0], q0 * xf0.x);
            atom_add(&acc[a0 + 1], q0 * xf0.y);
            atom_add(&acc[a0 + 2], q0 * xf0.z);
            atom_add(&acc[a0 + 3], q0 * xf0.w);
            const int a1 = ub1 + 1 + l * 4;
            atom_add(&acc[a1 + 0], q1 * xf1.x);
            atom_add(&acc[a1 + 1], q1 * xf1.y);
            atom_add(&acc[a1 + 2], q1 * xf1.z);
            atom_add(&acc[a1 + 3], q1 * xf1.w);
        } else if (l == DD4) {        // count column, one lane per group
            atom_add(&acc[ub0], q0);
            atom_add(&acc[ub1], q1);
        }
    }

    __syncthreads();
    // flush: nonzero-skip NATIVE global atomics into one of 64 replicas
    float* __restrict__ r = rep + (size_t)(blockIdx.x & (N_REP - 1)) * OUT_SIZE;
    for (int i = tid; i < OUT_SIZE; i += 512) {
        const float v = acc[i];
        if (v != 0.f) atom_add(&r[i], v);
    }
}

// ---------------------------------------------------------------------------
// Kernel R: sum 64 replicas -> d_out.  61 blocks x 256 thr.
// ---------------------------------------------------------------------------
__global__ __launch_bounds__(256) void reduce_kernel(
    const float* __restrict__ rep, float* __restrict__ out)
{
    const int i = blockIdx.x * 256 + threadIdx.x;
    float s = 0.f;
#pragma unroll 8
    for (int r = 0; r < N_REP; ++r)
        s += rep[(size_t)r * OUT_SIZE + i];
    out[i] = s;
}

extern "C" void kernel_launch(void* const* d_in, const int* in_sizes, int n_in,
                              void* d_out, int out_size, void* d_ws, size_t ws_size,
                              hipStream_t stream) {
    const float* features    = (const float*)d_in[0];
    const float* mu          = (const float*)d_in[1];
    const float* Coo_inv     = (const float*)d_in[2];
    // d_in[3] = Coo_logdet : unused (cancels in softmax)
    const float* log_prop    = (const float*)d_in[4];
    const float* noise_lp    = (const float*)d_in[5];
    const int*   cands       = (const int*)d_in[6];
    const int*   nid         = (const int*)d_in[7];
    const int*   obs_ix      = (const int*)d_in[8];
    float* out = (float*)d_out;

    char* ws = (char*)d_ws;
    float* w_buf = (float*)ws;                         // 128*256*60*4 = 7,864,320 B
    float* b_buf = (float*)(ws + 7864320);             // 128*256*4    =   131,072 B
    float* rep   = (float*)(ws + 7864320 + 131072);    // 64*15616*4   = 3,997,696 B

    hipMemsetAsync(rep, 0, (size_t)N_REP * OUT_SIZE * sizeof(float), stream);
    precompute_kernel<<<256, 128, 0, stream>>>(mu, Coo_inv, obs_ix, log_prop,
                                               w_buf, b_buf);
    spike_kernel<<<256, 512, 0, stream>>>(features, noise_lp, cands, nid,
                                          w_buf, b_buf, rep);
    reduce_kernel<<<61, 256, 0, stream>>>(rep, out);
}